// Round 2
// 1501.010 us; speedup vs baseline: 1.2450x; 1.2450x over previous
//
#include <hip/hip_runtime.h>

// ---------------------------------------------------------------------------
// Recurrent attention scan. B=512 T=512 C=64 H=128.
// 256-thread workgroup = 4 waves, all SAME h, 4 different 16-row b-tiles.
// grid = 128 h * 8 btile-groups = 1024 WGs; LDS/WG = 8KB shared We-frags +
// 4 * 8KB wave-private = 40960B -> exactly 4 WG/CU (160KB), 16 waves/CU.
// __launch_bounds__(256,4) caps unified VGPR+AGPR at 128/wave -> 4 waves/SIMD.
//
// vs failed round 1: DPP butterfly reverted to __builtin_amdgcn_update_dpp
// (inline-asm v_add_f32_dpp violates the VALU-write->DPP-read wait-state
// hazard: the post-RA hazard recognizer cannot see inside asm blocks ->
// garbage reductions -> NaN). LDS vector type-punning now uses may_alias
// types so TBAA cannot reorder packed writes vs b128 reads.
//
// Register fit for (256,4): att tile stores UNNORMALIZED softmax p (bf16);
// the per-row 1/sum (rinv) is carried in 4 VGPRs and folded into the next
// step's phase A: vacc = (p . Watt)*rinv + x . Win  (att-MFMAs first, scale,
// then x-MFMAs accumulate). Drops the pt[4][4] live range (16 VGPRs).
//
// Kept from round 1 (paper-verified): slot-permuted column layout
// (slot s holds channel c(s) = (s>>2) + (s&3)*16) for x/att/Y tiles and the
// gathered k-order of all weight fragments -> v_cvt_pk_bf16_f32 + b64 LDS
// writes, b64 dsum reads; weights pre-scaled by 2*log2e (Wcat) / log2e (We)
// so all exponentials are bare v_exp_f32 (exp2).
// ---------------------------------------------------------------------------

constexpr int Bsz = 512, Tsz = 512, Csz = 64, Hsz = 128;

typedef __attribute__((ext_vector_type(8))) short short8;
typedef __attribute__((may_alias)) short8 short8m;
typedef __attribute__((ext_vector_type(4))) float f32x4;
typedef __attribute__((ext_vector_type(2))) unsigned int u32x2;
typedef __attribute__((may_alias)) u32x2 u32x2m;

#define LOG2E     1.44269504088896f
#define SCALE_CAT 2.88539008177793f   // 2*log2e

// per-wave LDS region byte offsets inside priv[wave][8192]
#define XT 0        // x tile      [16][72] u16 (slot-permuted cols, 8 pad)
#define AT 2304     // att tile    [16][72] u16 (unnormalized p)
#define YT 4608     // tanh tile   [16][72] u16
#define OBF 6912    // out buffer  [16][20] f32
#define ROWB 144    // 72 u16 row pitch (bytes)
#define OPITCH 20

__device__ __forceinline__ unsigned short f2bf_rn(float f) {
    return (unsigned short)((__float_as_uint(f) + 0x8000u) >> 16);
}
__device__ __forceinline__ unsigned int pkbf(float lo, float hi) {
    unsigned int r;
    asm("v_cvt_pk_bf16_f32 %0, %1, %2" : "=v"(r) : "v"(lo), "v"(hi));
    return r;
}
// sum across each 16-lane row group, result in all 16 lanes.
// update_dpp builtin: compiler-generated DPP -> hazard nops handled.
template<int CTRL>
__device__ __forceinline__ float dpp_add(float v) {
    int t = __builtin_amdgcn_update_dpp(0, __float_as_int(v), CTRL, 0xF, 0xF, true);
    return v + __int_as_float(t);
}
__device__ __forceinline__ float row_sum16(float v) {
    v = dpp_add<0x128>(v);  // row_ror:8
    v = dpp_add<0x124>(v);  // row_ror:4
    v = dpp_add<0x4E>(v);   // quad_perm [2,3,0,1]
    v = dpp_add<0xB1>(v);   // quad_perm [1,0,3,2]
    return v;
}

// x[b][t][c] f32 -> xb[btile][t][row][64] bf16, slot-permuted:
// slot s holds c = (s>>2) + (s&3)*16
__global__ __launch_bounds__(256, 4)
void x_to_bf16_perm(const float* __restrict__ x, unsigned short* __restrict__ xb) {
    int g = blockIdx.x * 256 + threadIdx.x;      // B*T*8 threads, 8 slots each
    int row = g >> 3, k = g & 7;                 // row = b*512 + t
    int b = row >> 9, t = row & 511;
    const float* src = x + (size_t)row * 64;
    short8 f;
#pragma unroll
    for (int a = 0; a < 4; ++a) {
        float2 w = *(const float2*)(src + a * 16 + 2 * k);  // c = a*16+2k, +1
        f[a]     = (short)f2bf_rn(w.x);   // slot 8k+a   -> c = a*16+2k
        f[4 + a] = (short)f2bf_rn(w.y);   // slot 8k+4+a -> c = a*16+2k+1
    }
    size_t ob = ((size_t)((b >> 4) * Tsz + t) * 16 + (b & 15)) * 64 + k * 8;
    *(short8m*)(xb + ob) = f;
}

template<bool XPRE, bool OUTWS>
__global__ __launch_bounds__(256, 4)
void attn_scan(const float* __restrict__ xg,
               const unsigned short* __restrict__ xbg,
               const float* __restrict__ w_att,
               const float* __restrict__ w_in,
               const float* __restrict__ w_e,
               float* __restrict__ outg,
               float* __restrict__ outws)
{
    __shared__ __align__(16) unsigned short wefs[4096];   // We frags, shared (same h)
    __shared__ __align__(16) char priv[4][8192];          // wave-private tiles

    const int h     = blockIdx.x & (Hsz - 1);
    const int btg   = blockIdx.x >> 7;
    const int wave  = threadIdx.x >> 6;
    const int lane  = threadIdx.x & 63;
    const int btile = btg * 4 + wave;
    const int b0    = btile * 16;

    const int l15  = lane & 15;
    const int quad = lane >> 4;
    const int rowb = quad * 4;
    const int sr   = lane >> 2;          // staging row 0..15
    const int lq   = lane & 3;           // staging quarter

    // ---- cooperative We -> LDS, fragment layout, slot-permuted k, *log2e
    {
        const float* weh = w_e + (size_t)h * Csz * Csz;
#pragma unroll
        for (int i = 0; i < 2; ++i) {
            int tp = threadIdx.x * 2 + i;              // 0..511 tuples
            int ntks = tp >> 6, q = (tp >> 4) & 3, l = tp & 15;
            int ks = ntks & 1;
            int nt = ntks >> 1;
            int m = ks * 4 + q;
            const float* srcw = weh + (nt * 16 + l) * 64;
            short8 f;
#pragma unroll
            for (int j = 0; j < 8; ++j) {
                int kk = ((j & 3) << 4) + 2 * m + (j >> 2);   // = c(slot)
                f[j] = (short)f2bf_rn(srcw[kk] * LOG2E);
            }
            *(short8m*)(wefs + tp * 8) = f;
        }
    }

    // ---- Wcat (Win | Watt) -> registers, slot-permuted k, *2log2e
    short8 wcat[4][4];
    {
        const float* winh = w_in  + (size_t)h * Csz * Csz;
        const float* wath = w_att + (size_t)h * Csz * Csz;
#pragma unroll
        for (int nt = 0; nt < 4; ++nt) {
            const int c = nt * 16 + l15;
#pragma unroll
            for (int ks = 0; ks < 4; ++ks) {
                const float* srcw = ((ks < 2) ? winh : wath) + c * 64;
                const int m = (ks & 1) * 4 + quad;
                short8 f;
#pragma unroll
                for (int j = 0; j < 8; ++j) {
                    int kk = ((j & 3) << 4) + 2 * m + (j >> 2);
                    f[j] = (short)f2bf_rn(srcw[kk] * SCALE_CAT);
                }
                wcat[nt][ks] = f;
            }
        }
    }

    __syncthreads();   // wefs ready; only barrier in the kernel

    char* wb  = priv[wave];
    char* wbr = wb + l15 * ROWB + quad * 16;        // A-frag b128 read base
    char* wbd = wb + quad * (4 * ROWB) + l15 * 8;   // per-row b64 base
    const unsigned short* wfp = wefs + quad * 128 + l15 * 8;  // We B-frag base
    float* ob = (float*)(wb + OBF);

    // ---- init att0 = 1/64 (bf16 0x3C80): normalized, so rinv starts at 1
    {
        short8 kinit;
#pragma unroll
        for (int j = 0; j < 8; ++j) kinit[j] = (short)0x3C80;
#pragma unroll
        for (int i = 0; i < 3; ++i) {
            int idx = i * 64 + lane;
            if (idx < 144) *(short8m*)(wb + AT + idx * 16) = kinit;
        }
    }

    // ---- stage x_0 into XT
    {
        char* st = wb + XT + sr * ROWB + lq * 32;
        if (XPRE) {
            const unsigned short* xp = xbg + ((size_t)(btile * Tsz + 0) * 16 + sr) * 64 + lq * 16;
            *(short8m*)st        = *(const short8m*)xp;
            *(short8m*)(st + 16) = *(const short8m*)(xp + 8);
        } else {
            const float* xp = xg + ((size_t)(b0 + sr) * Tsz + 0) * 64 + lq * 4;
            float4 f0 = *(const float4*)(xp);
            float4 f1 = *(const float4*)(xp + 16);
            float4 f2 = *(const float4*)(xp + 32);
            float4 f3 = *(const float4*)(xp + 48);
            short8 lo, hi;
            lo[0]=(short)f2bf_rn(f0.x); lo[1]=(short)f2bf_rn(f1.x);
            lo[2]=(short)f2bf_rn(f2.x); lo[3]=(short)f2bf_rn(f3.x);
            lo[4]=(short)f2bf_rn(f0.y); lo[5]=(short)f2bf_rn(f1.y);
            lo[6]=(short)f2bf_rn(f2.y); lo[7]=(short)f2bf_rn(f3.y);
            hi[0]=(short)f2bf_rn(f0.z); hi[1]=(short)f2bf_rn(f1.z);
            hi[2]=(short)f2bf_rn(f2.z); hi[3]=(short)f2bf_rn(f3.z);
            hi[4]=(short)f2bf_rn(f0.w); hi[5]=(short)f2bf_rn(f1.w);
            hi[6]=(short)f2bf_rn(f2.w); hi[7]=(short)f2bf_rn(f3.w);
            *(short8m*)st = lo; *(short8m*)(st + 16) = hi;
        }
    }

    float rinv[4] = {1.f, 1.f, 1.f, 1.f};   // carried: 1/sum of prev step's p

    for (int t = 0; t < Tsz; ++t) {
        // -- prefetch x_{t+1} (staged at loop bottom) --
        const int tn = (t < Tsz - 1) ? t + 1 : t;
        short8 pxa, pxb;
        float4 pf0, pf1, pf2, pf3;
        if (XPRE) {
            const unsigned short* xp = xbg + ((size_t)(btile * Tsz + tn) * 16 + sr) * 64 + lq * 16;
            pxa = *(const short8m*)xp;
            pxb = *(const short8m*)(xp + 8);
        } else {
            const float* xp = xg + ((size_t)(b0 + sr) * Tsz + tn) * 64 + lq * 4;
            pf0 = *(const float4*)(xp);      pf1 = *(const float4*)(xp + 16);
            pf2 = *(const float4*)(xp + 32); pf3 = *(const float4*)(xp + 48);
        }

        f32x4 vacc[4];
        // -- phase A: vacc = (p . Watt^T)*rinv + x . Win^T  (pre-scaled 2log2e)
        {
            short8 aa0 = *(const short8m*)(wbr + AT);
            short8 aa1 = *(const short8m*)(wbr + AT + 64);
            f32x4 z = {0.f, 0.f, 0.f, 0.f};
#pragma unroll
            for (int nt = 0; nt < 4; ++nt) {
                vacc[nt] = __builtin_amdgcn_mfma_f32_16x16x32_bf16(aa0, wcat[nt][2], z, 0, 0, 0);
                vacc[nt] = __builtin_amdgcn_mfma_f32_16x16x32_bf16(aa1, wcat[nt][3], vacc[nt], 0, 0, 0);
            }
            short8 ax0 = *(const short8m*)(wbr + XT);
            short8 ax1 = *(const short8m*)(wbr + XT + 64);
#pragma unroll
            for (int nt = 0; nt < 4; ++nt)
#pragma unroll
                for (int rg = 0; rg < 4; ++rg)
                    vacc[nt][rg] *= rinv[rg];
#pragma unroll
            for (int nt = 0; nt < 4; ++nt) {
                vacc[nt] = __builtin_amdgcn_mfma_f32_16x16x32_bf16(ax0, wcat[nt][0], vacc[nt], 0, 0, 0);
                vacc[nt] = __builtin_amdgcn_mfma_f32_16x16x32_bf16(ax1, wcat[nt][1], vacc[nt], 0, 0, 0);
            }
        }

        // -- tanh: y = 1 - 2/(exp2(acc)+1); packed pairs -> Ytile (b64/row) --
#pragma unroll
        for (int rg = 0; rg < 4; ++rg) {
            float E0 = __builtin_amdgcn_exp2f(vacc[0][rg]);
            float E1 = __builtin_amdgcn_exp2f(vacc[1][rg]);
            float E2 = __builtin_amdgcn_exp2f(vacc[2][rg]);
            float E3 = __builtin_amdgcn_exp2f(vacc[3][rg]);
            float y0 = fmaf(-2.f, __builtin_amdgcn_rcpf(E0 + 1.f), 1.f);
            float y1 = fmaf(-2.f, __builtin_amdgcn_rcpf(E1 + 1.f), 1.f);
            float y2 = fmaf(-2.f, __builtin_amdgcn_rcpf(E2 + 1.f), 1.f);
            float y3 = fmaf(-2.f, __builtin_amdgcn_rcpf(E3 + 1.f), 1.f);
            u32x2 d;
            d[0] = pkbf(y0, y1);
            d[1] = pkbf(y2, y3);
            *(u32x2m*)(wbd + YT + rg * ROWB) = d;
        }

        // -- phase B: e = y . We^T (K=64), We frags from shared LDS --
        {
            short8 y0 = *(const short8m*)(wbr + YT);
            short8 y1 = *(const short8m*)(wbr + YT + 64);
            f32x4 z = {0.f, 0.f, 0.f, 0.f};
#pragma unroll
            for (int nt = 0; nt < 4; ++nt) {
                short8 w0 = *(const short8m*)(wfp + (nt * 2) * 512);
                short8 w1 = *(const short8m*)(wfp + (nt * 2 + 1) * 512);
                vacc[nt] = __builtin_amdgcn_mfma_f32_16x16x32_bf16(y0, w0, z, 0, 0, 0);
                vacc[nt] = __builtin_amdgcn_mfma_f32_16x16x32_bf16(y1, w1, vacc[nt], 0, 0, 0);
            }
        }

        // -- softmax numerators (no max: |e*log2e| <= 4.62), unnormalized
        //    store; out dot against x_t --
        float ssum[4], dsum[4];
#pragma unroll
        for (int rg = 0; rg < 4; ++rg) {
            u32x2 xd = *(const u32x2m*)(wbd + XT + rg * ROWB);
            float xv0 = __uint_as_float(xd[0] << 16);
            float xv1 = __uint_as_float(xd[0] & 0xffff0000u);
            float xv2 = __uint_as_float(xd[1] << 16);
            float xv3 = __uint_as_float(xd[1] & 0xffff0000u);
            float p0 = __builtin_amdgcn_exp2f(vacc[0][rg]);
            float p1 = __builtin_amdgcn_exp2f(vacc[1][rg]);
            float p2 = __builtin_amdgcn_exp2f(vacc[2][rg]);
            float p3 = __builtin_amdgcn_exp2f(vacc[3][rg]);
            u32x2 d;
            d[0] = pkbf(p0, p1);
            d[1] = pkbf(p2, p3);
            *(u32x2m*)(wbd + AT + rg * ROWB) = d;       // unnormalized p
            ssum[rg] = (p0 + p1) + (p2 + p3);
            dsum[rg] = fmaf(p0, xv0, fmaf(p1, xv1, fmaf(p2, xv2, p3 * xv3)));
        }
        float oval[4];
#pragma unroll
        for (int rg = 0; rg < 4; ++rg) {
            float s = row_sum16(ssum[rg]);
            float d = row_sum16(dsum[rg]);
            rinv[rg] = __builtin_amdgcn_rcpf(s);        // consumed next step
            oval[rg] = d * rinv[rg];
        }

        // -- out[b,t,h] --
        if (l15 < 4) {
            float v = oval[0];
            v = (l15 == 1) ? oval[1] : v;
            v = (l15 == 2) ? oval[2] : v;
            v = (l15 == 3) ? oval[3] : v;
            if (OUTWS) {
                ob[(rowb + l15) * OPITCH + (t & 15)] = v;
            } else {
                outg[(size_t)(b0 + rowb + l15) * (Tsz * Hsz) + (size_t)t * Hsz + h] = v;
            }
        }
        if (OUTWS && ((t & 15) == 15)) {
            float4 v = *(const float4*)&ob[sr * OPITCH + lq * 4];
            *(float4*)&outws[((size_t)h * Bsz + b0 + sr) * Tsz + (t - 15) + lq * 4] = v;
        }

        // -- stage x_{t+1} (after dsum reads; wave-private LDS is in-order) --
        char* st = wb + XT + sr * ROWB + lq * 32;
        if (XPRE) {
            *(short8m*)st = pxa; *(short8m*)(st + 16) = pxb;
        } else {
            short8 lo, hi;
            lo[0]=(short)f2bf_rn(pf0.x); lo[1]=(short)f2bf_rn(pf1.x);
            lo[2]=(short)f2bf_rn(pf2.x); lo[3]=(short)f2bf_rn(pf3.x);
            lo[4]=(short)f2bf_rn(pf0.y); lo[5]=(short)f2bf_rn(pf1.y);
            lo[6]=(short)f2bf_rn(pf2.y); lo[7]=(short)f2bf_rn(pf3.y);
            hi[0]=(short)f2bf_rn(pf0.z); hi[1]=(short)f2bf_rn(pf1.z);
            hi[2]=(short)f2bf_rn(pf2.z); hi[3]=(short)f2bf_rn(pf3.z);
            hi[4]=(short)f2bf_rn(pf0.w); hi[5]=(short)f2bf_rn(pf1.w);
            hi[6]=(short)f2bf_rn(pf2.w); hi[7]=(short)f2bf_rn(pf3.w);
            *(short8m*)st = lo; *(short8m*)(st + 16) = hi;
        }
    }
}

// ws[H][B][T] -> out[B][T][H], 64x64 (t,h) tiles per b
__global__ __launch_bounds__(256, 4)
void out_transpose(const float* __restrict__ ws, float* __restrict__ outg) {
    __shared__ float tile[64][65];
    const int t0 = blockIdx.x * 64;
    const int h0 = blockIdx.y * 64;
    const int b  = blockIdx.z;
    const int tx = threadIdx.x & 63;
    const int wy = threadIdx.x >> 6;
#pragma unroll
    for (int i = 0; i < 16; ++i) {
        int hr = wy * 16 + i;
        tile[hr][tx] = ws[((size_t)(h0 + hr) * Bsz + b) * Tsz + t0 + tx];
    }
    __syncthreads();
#pragma unroll
    for (int i = 0; i < 16; ++i) {
        int tt = wy * 16 + i;
        outg[((size_t)b * Tsz + t0 + tt) * Hsz + h0 + tx] = tile[tx][tt];
    }
}

extern "C" void kernel_launch(void* const* d_in, const int* in_sizes, int n_in,
                              void* d_out, int out_size, void* d_ws, size_t ws_size,
                              hipStream_t stream) {
    // setup_inputs order: x, weight_att, weight_input, weight_e
    const float* x     = (const float*)d_in[0];
    const float* w_att = (const float*)d_in[1];
    const float* w_in  = (const float*)d_in[2];
    const float* w_e   = (const float*)d_in[3];
    float* out = (float*)d_out;

    const size_t XB = (size_t)Bsz * Tsz * Csz * sizeof(unsigned short);  // 33.5 MB
    const size_t OB = (size_t)Bsz * Tsz * Hsz * sizeof(float);           // 134 MB
    unsigned short* xb  = (unsigned short*)d_ws;
    float*          ows = (float*)((char*)d_ws + XB);

    const int xblocks = Bsz * Tsz * 8 / 256;      // 8192
    dim3 scan_grid(Hsz * (Bsz / 64));             // 1024 WGs of 4 waves

    if (ws_size >= XB + OB) {
        x_to_bf16_perm<<<xblocks, 256, 0, stream>>>(x, xb);
        attn_scan<true, true><<<scan_grid, 256, 0, stream>>>(x, xb, w_att, w_in, w_e, out, ows);
        dim3 tg(Tsz / 64, Hsz / 64, Bsz);
        out_transpose<<<tg, 256, 0, stream>>>(ows, out);
    } else if (ws_size >= XB) {
        x_to_bf16_perm<<<xblocks, 256, 0, stream>>>(x, xb);
        attn_scan<true, false><<<scan_grid, 256, 0, stream>>>(x, xb, w_att, w_in, w_e, out, nullptr);
    } else {
        attn_scan<false, false><<<scan_grid, 256, 0, stream>>>(x, nullptr, w_att, w_in, w_e, out, nullptr);
    }
}

// Round 3
// 1351.914 us; speedup vs baseline: 1.3823x; 1.1103x over previous
//
#include <hip/hip_runtime.h>

// ---------------------------------------------------------------------------
// Recurrent attention scan. B=512 T=512 C=64 H=128.
// 256-thread workgroup = 4 waves, all SAME h, 4 different 16-row b-tiles.
// grid = 1024 WGs; LDS/WG = 8KB shared We-frags + 4*4608B wave-private
// (AT + YT only) = 26624B -> 4 WG/CU with slack (round 2's 40960B == exact
// 160KB fit got only 3 WG/CU resident -> occupancy-capped at 35%).
//
// vs round 2 (1501us, VALU-issue-bound, 75% VALUBusy):
//  - ssum via MFMA(p_frag, ones): D[r][n]=ssum[r] in every col -> sacc[rg]
//    IS ssum[rowb+rg] per lane (the exact layout rinv needs). No DPP.
//  - dsum via MFMA(p_frag, x_frag): diag(P.X^T) = out_t. A/B frags share
//    the same gather on gfx950, so x A-frags serve as the B operand.
//    Diag lives on lanes l15>>2==quad at rg=l15&3 (cndmask chains).
//    Deletes ~100 VALU instrs/step (64 DPP + extracts + FMAs) for +4 MFMA.
//  - XT tile deleted: x A-frags read directly from the permuted xb
//    workspace (frag-addressable: row l15, slots quad*8.. at l15*64+quad*8).
//  - OBF deleted: direct predicated b32 stores to outws[H][B][T]; each
//    64B line is written by one lane (16 consecutive t) -> single-owner.
// Registers: wcat 64 + ones 4 + x frags 16 + vacc 16 + rinv 4 + misc ~20
// ~= 124 <= 128 cap of __launch_bounds__(256,4). AT is re-read at the top
// of each step (not carried) to keep aa liveness short.
// ---------------------------------------------------------------------------

constexpr int Bsz = 512, Tsz = 512, Csz = 64, Hsz = 128;

typedef __attribute__((ext_vector_type(8))) short short8;
typedef __attribute__((may_alias)) short8 short8m;
typedef __attribute__((ext_vector_type(4))) float f32x4;
typedef __attribute__((ext_vector_type(2))) unsigned int u32x2;
typedef __attribute__((may_alias)) u32x2 u32x2m;

#define LOG2E     1.44269504088896f
#define SCALE_CAT 2.88539008177793f   // 2*log2e

// per-wave LDS region byte offsets inside priv[wave][4608]
#define AT 0        // att tile (unnormalized p) [16][72] u16, slot-permuted
#define YT 2304     // tanh tile                 [16][72] u16
#define ROWB 144    // 72 u16 row pitch (bytes)

__device__ __forceinline__ unsigned short f2bf_rn(float f) {
    return (unsigned short)((__float_as_uint(f) + 0x8000u) >> 16);
}
__device__ __forceinline__ unsigned int pkbf(float lo, float hi) {
    unsigned int r;
    asm("v_cvt_pk_bf16_f32 %0, %1, %2" : "=v"(r) : "v"(lo), "v"(hi));
    return r;
}

// x[b][t][c] f32 -> xb[btile][t][row16][64] bf16, slot-permuted:
// slot s holds c = (s>>2) + (s&3)*16   (unchanged from round 2, proven)
__global__ __launch_bounds__(256, 4)
void x_to_bf16_perm(const float* __restrict__ x, unsigned short* __restrict__ xb) {
    int g = blockIdx.x * 256 + threadIdx.x;      // B*T*8 threads, 8 slots each
    int row = g >> 3, k = g & 7;                 // row = b*512 + t
    int b = row >> 9, t = row & 511;
    const float* src = x + (size_t)row * 64;
    short8 f;
#pragma unroll
    for (int a = 0; a < 4; ++a) {
        float2 w = *(const float2*)(src + a * 16 + 2 * k);  // c = a*16+2k, +1
        f[a]     = (short)f2bf_rn(w.x);   // slot 8k+a   -> c = a*16+2k
        f[4 + a] = (short)f2bf_rn(w.y);   // slot 8k+4+a -> c = a*16+2k+1
    }
    size_t ob = ((size_t)((b >> 4) * Tsz + t) * 16 + (b & 15)) * 64 + k * 8;
    *(short8m*)(xb + ob) = f;
}

// !XPRE fallback: gather one x A-frag pair straight from f32 x (slow path)
__device__ __forceinline__ void load_xfrag_f32(const float* src, int quad,
                                               short8& f0, short8& f1) {
#pragma unroll
    for (int hh = 0; hh < 2; ++hh) {
        short8 f;
        const int K = hh * 8 + quad * 2;
#pragma unroll
        for (int m = 0; m < 4; ++m) {
            float2 w = *(const float2*)(src + K + 16 * m);
            f[m]     = (short)f2bf_rn(w.x);
            f[m + 4] = (short)f2bf_rn(w.y);
        }
        if (hh == 0) f0 = f; else f1 = f;
    }
}

template<bool XPRE, bool OUTWS>
__global__ __launch_bounds__(256, 4)
void attn_scan(const float* __restrict__ xg,
               const unsigned short* __restrict__ xbg,
               const float* __restrict__ w_att,
               const float* __restrict__ w_in,
               const float* __restrict__ w_e,
               float* __restrict__ outg,
               float* __restrict__ outws)
{
    __shared__ __align__(16) unsigned short wefs[4096];   // We frags, shared (same h)
    __shared__ __align__(16) char priv[4][4608];          // wave-private AT+YT

    const int h     = blockIdx.x & (Hsz - 1);
    const int btg   = blockIdx.x >> 7;
    const int wave  = threadIdx.x >> 6;
    const int lane  = threadIdx.x & 63;
    const int btile = btg * 4 + wave;
    const int b0    = btile * 16;

    const int l15  = lane & 15;
    const int quad = lane >> 4;
    const int rowb = quad * 4;

    // ---- cooperative We -> LDS, fragment layout, slot-permuted k, *log2e
    {
        const float* weh = w_e + (size_t)h * Csz * Csz;
#pragma unroll
        for (int i = 0; i < 2; ++i) {
            int tp = threadIdx.x * 2 + i;              // 0..511 tuples
            int ntks = tp >> 6, q = (tp >> 4) & 3, l = tp & 15;
            int ks = ntks & 1;
            int nt = ntks >> 1;
            int m = ks * 4 + q;
            const float* srcw = weh + (nt * 16 + l) * 64;
            short8 f;
#pragma unroll
            for (int j = 0; j < 8; ++j) {
                int kk = ((j & 3) << 4) + 2 * m + (j >> 2);   // = c(slot)
                f[j] = (short)f2bf_rn(srcw[kk] * LOG2E);
            }
            *(short8m*)(wefs + tp * 8) = f;
        }
    }

    // ---- Wcat (Win | Watt) -> registers, slot-permuted k, *2log2e
    short8 wcat[4][4];
    {
        const float* winh = w_in  + (size_t)h * Csz * Csz;
        const float* wath = w_att + (size_t)h * Csz * Csz;
#pragma unroll
        for (int nt = 0; nt < 4; ++nt) {
            const int c = nt * 16 + l15;
#pragma unroll
            for (int ks = 0; ks < 4; ++ks) {
                const float* srcw = ((ks < 2) ? winh : wath) + c * 64;
                const int m = (ks & 1) * 4 + quad;
                short8 f;
#pragma unroll
                for (int j = 0; j < 8; ++j) {
                    int kk = ((j & 3) << 4) + 2 * m + (j >> 2);
                    f[j] = (short)f2bf_rn(srcw[kk] * SCALE_CAT);
                }
                wcat[nt][ks] = f;
            }
        }
    }

    __syncthreads();   // wefs ready; only barrier in the kernel

    char* wb  = priv[wave];
    char* wbr = wb + l15 * ROWB + quad * 16;        // A-frag b128 read base
    char* wbd = wb + quad * (4 * ROWB) + l15 * 8;   // per-row b64 write base
    const unsigned short* wfp = wefs + quad * 128 + l15 * 8;  // We B-frag base

    // ones B-frag (bf16 1.0): for ssum MFMA
    short8 ones8;
#pragma unroll
    for (int j = 0; j < 8; ++j) ones8[j] = (short)0x3F80;

    // ---- init att0 = 1/64 (bf16 0x3C80): normalized, so rinv starts at 1
    {
        short8 kinit;
#pragma unroll
        for (int j = 0; j < 8; ++j) kinit[j] = (short)0x3C80;
#pragma unroll
        for (int i = 0; i < 3; ++i) {
            int idx = i * 64 + lane;
            if (idx < 144) *(short8m*)(wb + AT + idx * 16) = kinit;
        }
    }

    // ---- x A-frag source (frag-addressable permuted layout)
    const unsigned short* xfp = nullptr;
    if (XPRE)
        xfp = xbg + (size_t)btile * Tsz * 1024 + l15 * 64 + quad * 8;

    // ---- out addressing: diag lanes (l15>>2==quad) own row rowb+(l15&3)
    const int  k3     = l15 & 3;
    const int  orow   = rowb + k3;
    const bool isdiag = ((l15 >> 2) == quad);
    float* op;
    if (OUTWS) op = outws + ((size_t)h * Bsz + b0 + orow) * Tsz;
    else       op = outg + (size_t)(b0 + orow) * (Tsz * Hsz) + h;

    // ---- load x_0 frags
    short8 axc0, axc1;
    if (XPRE) {
        axc0 = *(const short8m*)(xfp);
        axc1 = *(const short8m*)(xfp + 32);
    } else {
        load_xfrag_f32(xg + ((size_t)(b0 + l15) * Tsz) * 64, quad, axc0, axc1);
    }

    float rinv[4] = {1.f, 1.f, 1.f, 1.f};   // 1/ssum of prev step's p

    for (int t = 0; t < Tsz; ++t) {
        // -- prefetch x_{t+1} frags --
        const int tn = (t < Tsz - 1) ? t + 1 : t;
        short8 axn0, axn1;
        if (XPRE) {
            axn0 = *(const short8m*)(xfp + (size_t)tn * 1024);
            axn1 = *(const short8m*)(xfp + (size_t)tn * 1024 + 32);
        } else {
            load_xfrag_f32(xg + ((size_t)(b0 + l15) * Tsz + tn) * 64, quad, axn0, axn1);
        }

        f32x4 vacc[4];
        // -- phase A: vacc = (p . Watt^T)*rinv + x . Win^T  (pre-scaled 2log2e)
        {
            short8 aa0 = *(const short8m*)(wbr + AT);
            short8 aa1 = *(const short8m*)(wbr + AT + 64);
            f32x4 z = {0.f, 0.f, 0.f, 0.f};
#pragma unroll
            for (int nt = 0; nt < 4; ++nt) {
                vacc[nt] = __builtin_amdgcn_mfma_f32_16x16x32_bf16(aa0, wcat[nt][2], z, 0, 0, 0);
                vacc[nt] = __builtin_amdgcn_mfma_f32_16x16x32_bf16(aa1, wcat[nt][3], vacc[nt], 0, 0, 0);
            }
#pragma unroll
            for (int nt = 0; nt < 4; ++nt)
#pragma unroll
                for (int rg = 0; rg < 4; ++rg)
                    vacc[nt][rg] *= rinv[rg];
#pragma unroll
            for (int nt = 0; nt < 4; ++nt) {
                vacc[nt] = __builtin_amdgcn_mfma_f32_16x16x32_bf16(axc0, wcat[nt][0], vacc[nt], 0, 0, 0);
                vacc[nt] = __builtin_amdgcn_mfma_f32_16x16x32_bf16(axc1, wcat[nt][1], vacc[nt], 0, 0, 0);
            }
        }

        // -- tanh: y = 1 - 2/(exp2(acc)+1); packed pairs -> Ytile (b64/row) --
#pragma unroll
        for (int rg = 0; rg < 4; ++rg) {
            float E0 = __builtin_amdgcn_exp2f(vacc[0][rg]);
            float E1 = __builtin_amdgcn_exp2f(vacc[1][rg]);
            float E2 = __builtin_amdgcn_exp2f(vacc[2][rg]);
            float E3 = __builtin_amdgcn_exp2f(vacc[3][rg]);
            float y0 = fmaf(-2.f, __builtin_amdgcn_rcpf(E0 + 1.f), 1.f);
            float y1 = fmaf(-2.f, __builtin_amdgcn_rcpf(E1 + 1.f), 1.f);
            float y2 = fmaf(-2.f, __builtin_amdgcn_rcpf(E2 + 1.f), 1.f);
            float y3 = fmaf(-2.f, __builtin_amdgcn_rcpf(E3 + 1.f), 1.f);
            u32x2 d;
            d[0] = pkbf(y0, y1);
            d[1] = pkbf(y2, y3);
            *(u32x2m*)(wbd + YT + rg * ROWB) = d;
        }

        // -- phase B: e = y . We^T (K=64), We frags from shared LDS --
        {
            short8 y0 = *(const short8m*)(wbr + YT);
            short8 y1 = *(const short8m*)(wbr + YT + 64);
            f32x4 z = {0.f, 0.f, 0.f, 0.f};
#pragma unroll
            for (int nt = 0; nt < 4; ++nt) {
                short8 w0 = *(const short8m*)(wfp + (nt * 2) * 512);
                short8 w1 = *(const short8m*)(wfp + (nt * 2 + 1) * 512);
                vacc[nt] = __builtin_amdgcn_mfma_f32_16x16x32_bf16(y0, w0, z, 0, 0, 0);
                vacc[nt] = __builtin_amdgcn_mfma_f32_16x16x32_bf16(y1, w1, vacc[nt], 0, 0, 0);
            }
        }

        // -- softmax numerators (no max: |e*log2e| <= 4.62) -> AT (bf16) --
#pragma unroll
        for (int rg = 0; rg < 4; ++rg) {
            float p0 = __builtin_amdgcn_exp2f(vacc[0][rg]);
            float p1 = __builtin_amdgcn_exp2f(vacc[1][rg]);
            float p2 = __builtin_amdgcn_exp2f(vacc[2][rg]);
            float p3 = __builtin_amdgcn_exp2f(vacc[3][rg]);
            u32x2 d;
            d[0] = pkbf(p0, p1);
            d[1] = pkbf(p2, p3);
            *(u32x2m*)(wbd + AT + rg * ROWB) = d;       // unnormalized p
        }

        // -- read back p A-frags; ssum/dsum on the MFMA pipe --
        {
            short8 pa0 = *(const short8m*)(wbr + AT);
            short8 pa1 = *(const short8m*)(wbr + AT + 64);
            f32x4 z = {0.f, 0.f, 0.f, 0.f};
            f32x4 sacc = __builtin_amdgcn_mfma_f32_16x16x32_bf16(pa0, ones8, z, 0, 0, 0);
            sacc = __builtin_amdgcn_mfma_f32_16x16x32_bf16(pa1, ones8, sacc, 0, 0, 0);
            f32x4 dacc = __builtin_amdgcn_mfma_f32_16x16x32_bf16(pa0, axc0, z, 0, 0, 0);
            dacc = __builtin_amdgcn_mfma_f32_16x16x32_bf16(pa1, axc1, dacc, 0, 0, 0);

            // rinv[rg] = 1/ssum[rowb+rg]  (every lane, layout matches vacc)
            rinv[0] = __builtin_amdgcn_rcpf(sacc[0]);
            rinv[1] = __builtin_amdgcn_rcpf(sacc[1]);
            rinv[2] = __builtin_amdgcn_rcpf(sacc[2]);
            rinv[3] = __builtin_amdgcn_rcpf(sacc[3]);

            // out_t = diag(dacc)*rinv on diag lanes
            float dv = dacc[0];
            dv = (k3 == 1) ? dacc[1] : dv;
            dv = (k3 == 2) ? dacc[2] : dv;
            dv = (k3 == 3) ? dacc[3] : dv;
            float rv = rinv[0];
            rv = (k3 == 1) ? rinv[1] : rv;
            rv = (k3 == 2) ? rinv[2] : rv;
            rv = (k3 == 3) ? rinv[3] : rv;
            if (isdiag) {
                if (OUTWS) op[t] = dv * rv;
                else       op[(size_t)t * Hsz] = dv * rv;
            }
        }

        // -- rotate x frags --
        axc0 = axn0; axc1 = axn1;
    }
}

// ws[H][B][T] -> out[B][T][H], 64x64 (t,h) tiles per b
__global__ __launch_bounds__(256, 4)
void out_transpose(const float* __restrict__ ws, float* __restrict__ outg) {
    __shared__ float tile[64][65];
    const int t0 = blockIdx.x * 64;
    const int h0 = blockIdx.y * 64;
    const int b  = blockIdx.z;
    const int tx = threadIdx.x & 63;
    const int wy = threadIdx.x >> 6;
#pragma unroll
    for (int i = 0; i < 16; ++i) {
        int hr = wy * 16 + i;
        tile[hr][tx] = ws[((size_t)(h0 + hr) * Bsz + b) * Tsz + t0 + tx];
    }
    __syncthreads();
#pragma unroll
    for (int i = 0; i < 16; ++i) {
        int tt = wy * 16 + i;
        outg[((size_t)b * Tsz + t0 + tt) * Hsz + h0 + tx] = tile[tx][tt];
    }
}

extern "C" void kernel_launch(void* const* d_in, const int* in_sizes, int n_in,
                              void* d_out, int out_size, void* d_ws, size_t ws_size,
                              hipStream_t stream) {
    // setup_inputs order: x, weight_att, weight_input, weight_e
    const float* x     = (const float*)d_in[0];
    const float* w_att = (const float*)d_in[1];
    const float* w_in  = (const float*)d_in[2];
    const float* w_e   = (const float*)d_in[3];
    float* out = (float*)d_out;

    const size_t XB = (size_t)Bsz * Tsz * Csz * sizeof(unsigned short);  // 33.5 MB
    const size_t OB = (size_t)Bsz * Tsz * Hsz * sizeof(float);           // 134 MB
    unsigned short* xb  = (unsigned short*)d_ws;
    float*          ows = (float*)((char*)d_ws + XB);

    const int xblocks = Bsz * Tsz * 8 / 256;      // 8192
    dim3 scan_grid(Hsz * (Bsz / 64));             // 1024 WGs of 4 waves

    if (ws_size >= XB + OB) {
        x_to_bf16_perm<<<xblocks, 256, 0, stream>>>(x, xb);
        attn_scan<true, true><<<scan_grid, 256, 0, stream>>>(x, xb, w_att, w_in, w_e, out, ows);
        dim3 tg(Tsz / 64, Hsz / 64, Bsz);
        out_transpose<<<tg, 256, 0, stream>>>(ows, out);
    } else if (ws_size >= XB) {
        x_to_bf16_perm<<<xblocks, 256, 0, stream>>>(x, xb);
        attn_scan<true, false><<<scan_grid, 256, 0, stream>>>(x, xb, w_att, w_in, w_e, out, nullptr);
    } else {
        attn_scan<false, false><<<scan_grid, 256, 0, stream>>>(x, nullptr, w_att, w_in, w_e, out, nullptr);
    }
}

// Round 6
// 1304.944 us; speedup vs baseline: 1.4320x; 1.0360x over previous
//
#include <hip/hip_runtime.h>

// ---------------------------------------------------------------------------
// Recurrent attention scan. B=512 T=512 C=64 H=128.
// 256-thread WG = 4 waves, SAME h, 4 different 16-row b-tiles. grid = 1024.
//
// Round 6 = round 3 (passed, 1352us) MINUS the x-prefetch registers.
// History: round 4 (4-change bundle) and round 5 (bisected: Win->LDS only)
// both failed numerically despite triple-verified index math -> the
// Win-to-LDS lever is abandoned as empirically unreliable.
// Occupancy theory refined: VGPR_Count=64 is arch-only; wcat (64 frags regs)
// lives in AGPRs -> unified ~132-136, BARELY over the 128 cap for
// 4 waves/SIMD -> 3 waves (35% measured). Cutting the axn0/axn1 prefetch
// (8 VGPRs) + tn clamp logic should tip unified <= 128 -> 4 waves/SIMD.
// Latency cost: x load at top of iter has ~100cy slack (8 att-MFMAs + rinv
// muls) vs ~200cy L2 hit; 3-4 co-resident waves cover the rest.
// EVERYTHING else is byte-identical to round 3: wcat[4][4] register frags,
// wefs shared LDS, AT/YT tiles, MFMA-pipe ssum/dsum, diag out stores.
// ---------------------------------------------------------------------------

constexpr int Bsz = 512, Tsz = 512, Csz = 64, Hsz = 128;

typedef __attribute__((ext_vector_type(8))) short short8;
typedef __attribute__((may_alias)) short8 short8m;
typedef __attribute__((ext_vector_type(4))) float f32x4;
typedef __attribute__((ext_vector_type(2))) unsigned int u32x2;
typedef __attribute__((may_alias)) u32x2 u32x2m;

#define LOG2E     1.44269504088896f
#define SCALE_CAT 2.88539008177793f   // 2*log2e

// per-wave LDS region byte offsets inside priv[wave][4608]
#define AT 0        // att tile (unnormalized p) [16][72] u16, slot-permuted
#define YT 2304     // tanh tile                 [16][72] u16
#define ROWB 144    // 72 u16 row pitch (bytes)

__device__ __forceinline__ unsigned short f2bf_rn(float f) {
    return (unsigned short)((__float_as_uint(f) + 0x8000u) >> 16);
}
__device__ __forceinline__ unsigned int pkbf(float lo, float hi) {
    unsigned int r;
    asm("v_cvt_pk_bf16_f32 %0, %1, %2" : "=v"(r) : "v"(lo), "v"(hi));
    return r;
}

// x[b][t][c] f32 -> xb[btile][t][row16][64] bf16, slot-permuted:
// slot s holds c = (s>>2) + (s&3)*16
__global__ __launch_bounds__(256, 4)
void x_to_bf16_perm(const float* __restrict__ x, unsigned short* __restrict__ xb) {
    int g = blockIdx.x * 256 + threadIdx.x;      // B*T*8 threads, 8 slots each
    int row = g >> 3, k = g & 7;                 // row = b*512 + t
    int b = row >> 9, t = row & 511;
    const float* src = x + (size_t)row * 64;
    short8 f;
#pragma unroll
    for (int a = 0; a < 4; ++a) {
        float2 w = *(const float2*)(src + a * 16 + 2 * k);  // c = a*16+2k, +1
        f[a]     = (short)f2bf_rn(w.x);   // slot 8k+a   -> c = a*16+2k
        f[4 + a] = (short)f2bf_rn(w.y);   // slot 8k+4+a -> c = a*16+2k+1
    }
    size_t ob = ((size_t)((b >> 4) * Tsz + t) * 16 + (b & 15)) * 64 + k * 8;
    *(short8m*)(xb + ob) = f;
}

// !XPRE fallback: gather one x A-frag pair straight from f32 x (slow path)
__device__ __forceinline__ void load_xfrag_f32(const float* src, int quad,
                                               short8& f0, short8& f1) {
#pragma unroll
    for (int hh = 0; hh < 2; ++hh) {
        short8 f;
        const int K = hh * 8 + quad * 2;
#pragma unroll
        for (int m = 0; m < 4; ++m) {
            float2 w = *(const float2*)(src + K + 16 * m);
            f[m]     = (short)f2bf_rn(w.x);
            f[m + 4] = (short)f2bf_rn(w.y);
        }
        if (hh == 0) f0 = f; else f1 = f;
    }
}

template<bool XPRE, bool OUTWS>
__global__ __launch_bounds__(256, 4)
void attn_scan(const float* __restrict__ xg,
               const unsigned short* __restrict__ xbg,
               const float* __restrict__ w_att,
               const float* __restrict__ w_in,
               const float* __restrict__ w_e,
               float* __restrict__ outg,
               float* __restrict__ outws)
{
    __shared__ __align__(16) unsigned short wefs[4096];   // We frags (shared, same h)
    __shared__ __align__(16) char priv[4][4608];          // wave-private AT+YT

    const int h     = blockIdx.x & (Hsz - 1);
    const int btg   = blockIdx.x >> 7;
    const int wave  = threadIdx.x >> 6;
    const int lane  = threadIdx.x & 63;
    const int btile = btg * 4 + wave;
    const int b0    = btile * 16;

    const int l15  = lane & 15;
    const int quad = lane >> 4;
    const int rowb = quad * 4;

    // ---- cooperative We -> LDS, fragment layout, slot-permuted k, *log2e
    {
        const float* weh = w_e + (size_t)h * Csz * Csz;
#pragma unroll
        for (int i = 0; i < 2; ++i) {
            int tp = threadIdx.x * 2 + i;              // 0..511 tuples
            int ntks = tp >> 6, q = (tp >> 4) & 3, l = tp & 15;
            int ks = ntks & 1, nt = ntks >> 1;
            int m = ks * 4 + q;
            const float* srcw = weh + (nt * 16 + l) * 64;
            short8 f;
#pragma unroll
            for (int j = 0; j < 8; ++j) {
                int kk = ((j & 3) << 4) + 2 * m + (j >> 2);   // = c(slot)
                f[j] = (short)f2bf_rn(srcw[kk] * LOG2E);
            }
            *(short8m*)(wefs + tp * 8) = f;
        }
    }

    // ---- Wcat (Win | Watt) -> registers, slot-permuted k, *2log2e
    short8 wcat[4][4];
    {
        const float* winh = w_in  + (size_t)h * Csz * Csz;
        const float* wath = w_att + (size_t)h * Csz * Csz;
#pragma unroll
        for (int nt = 0; nt < 4; ++nt) {
            const int c = nt * 16 + l15;
#pragma unroll
            for (int ks = 0; ks < 4; ++ks) {
                const float* srcw = ((ks < 2) ? winh : wath) + c * 64;
                const int m = (ks & 1) * 4 + quad;
                short8 f;
#pragma unroll
                for (int j = 0; j < 8; ++j) {
                    int kk = ((j & 3) << 4) + 2 * m + (j >> 2);
                    f[j] = (short)f2bf_rn(srcw[kk] * SCALE_CAT);
                }
                wcat[nt][ks] = f;
            }
        }
    }

    __syncthreads();   // wefs ready; only barrier in the kernel

    char* wb  = priv[wave];
    char* wbr = wb + l15 * ROWB + quad * 16;        // A-frag b128 read base
    char* wbd = wb + quad * (4 * ROWB) + l15 * 8;   // per-row b64 write base
    const unsigned short* wfpe = wefs + quad * 128 + l15 * 8;  // We B-frag base

    // ones B-frag (bf16 1.0): for ssum MFMA
    short8 ones8;
#pragma unroll
    for (int j = 0; j < 8; ++j) ones8[j] = (short)0x3F80;

    // ---- init att0 = 1/64 (bf16 0x3C80): normalized, so rinv starts at 1
    {
        short8 kinit;
#pragma unroll
        for (int j = 0; j < 8; ++j) kinit[j] = (short)0x3C80;
#pragma unroll
        for (int i = 0; i < 3; ++i) {
            int idx = i * 64 + lane;
            if (idx < 144) *(short8m*)(wb + AT + idx * 16) = kinit;
        }
    }

    // ---- x A-frag source (frag-addressable permuted layout)
    const unsigned short* xfp = nullptr;
    if (XPRE)
        xfp = xbg + (size_t)btile * Tsz * 1024 + l15 * 64 + quad * 8;

    // ---- out addressing: diag lanes (l15>>2==quad) own row rowb+(l15&3)
    const int  k3     = l15 & 3;
    const int  orow   = rowb + k3;
    const bool isdiag = ((l15 >> 2) == quad);
    float* op;
    if (OUTWS) op = outws + ((size_t)h * Bsz + b0 + orow) * Tsz;
    else       op = outg + (size_t)(b0 + orow) * (Tsz * Hsz) + h;

    float rinv[4] = {1.f, 1.f, 1.f, 1.f};   // 1/ssum of prev step's p

    for (int t = 0; t < Tsz; ++t) {
        // -- load x_t frags (no prefetch: saves 8 VGPRs; ~100cy slack below) --
        short8 axc0, axc1;
        if (XPRE) {
            axc0 = *(const short8m*)(xfp + (size_t)t * 1024);
            axc1 = *(const short8m*)(xfp + (size_t)t * 1024 + 32);
        } else {
            load_xfrag_f32(xg + ((size_t)(b0 + l15) * Tsz + t) * 64, quad, axc0, axc1);
        }

        f32x4 vacc[4];
        // -- phase A: vacc = (p . Watt^T)*rinv + x . Win^T (pre-scaled 2log2e)
        //    att MFMAs first (x load latency hides under them) --
        {
            short8 aa0 = *(const short8m*)(wbr + AT);
            short8 aa1 = *(const short8m*)(wbr + AT + 64);
            f32x4 z = {0.f, 0.f, 0.f, 0.f};
#pragma unroll
            for (int nt = 0; nt < 4; ++nt) {
                vacc[nt] = __builtin_amdgcn_mfma_f32_16x16x32_bf16(aa0, wcat[nt][2], z, 0, 0, 0);
                vacc[nt] = __builtin_amdgcn_mfma_f32_16x16x32_bf16(aa1, wcat[nt][3], vacc[nt], 0, 0, 0);
            }
#pragma unroll
            for (int nt = 0; nt < 4; ++nt)
#pragma unroll
                for (int rg = 0; rg < 4; ++rg)
                    vacc[nt][rg] *= rinv[rg];
#pragma unroll
            for (int nt = 0; nt < 4; ++nt) {
                vacc[nt] = __builtin_amdgcn_mfma_f32_16x16x32_bf16(axc0, wcat[nt][0], vacc[nt], 0, 0, 0);
                vacc[nt] = __builtin_amdgcn_mfma_f32_16x16x32_bf16(axc1, wcat[nt][1], vacc[nt], 0, 0, 0);
            }
        }

        // -- tanh: y = 1 - 2/(exp2(acc)+1); packed pairs -> Ytile (b64/row) --
#pragma unroll
        for (int rg = 0; rg < 4; ++rg) {
            float E0 = __builtin_amdgcn_exp2f(vacc[0][rg]);
            float E1 = __builtin_amdgcn_exp2f(vacc[1][rg]);
            float E2 = __builtin_amdgcn_exp2f(vacc[2][rg]);
            float E3 = __builtin_amdgcn_exp2f(vacc[3][rg]);
            float y0 = fmaf(-2.f, __builtin_amdgcn_rcpf(E0 + 1.f), 1.f);
            float y1 = fmaf(-2.f, __builtin_amdgcn_rcpf(E1 + 1.f), 1.f);
            float y2 = fmaf(-2.f, __builtin_amdgcn_rcpf(E2 + 1.f), 1.f);
            float y3 = fmaf(-2.f, __builtin_amdgcn_rcpf(E3 + 1.f), 1.f);
            u32x2 d;
            d[0] = pkbf(y0, y1);
            d[1] = pkbf(y2, y3);
            *(u32x2m*)(wbd + YT + rg * ROWB) = d;
        }

        // -- phase B: e = y . We^T (K=64), We frags from shared LDS --
        {
            short8 y0 = *(const short8m*)(wbr + YT);
            short8 y1 = *(const short8m*)(wbr + YT + 64);
            f32x4 z = {0.f, 0.f, 0.f, 0.f};
#pragma unroll
            for (int nt = 0; nt < 4; ++nt) {
                short8 w0 = *(const short8m*)(wfpe + (nt * 2) * 512);
                short8 w1 = *(const short8m*)(wfpe + (nt * 2 + 1) * 512);
                vacc[nt] = __builtin_amdgcn_mfma_f32_16x16x32_bf16(y0, w0, z, 0, 0, 0);
                vacc[nt] = __builtin_amdgcn_mfma_f32_16x16x32_bf16(y1, w1, vacc[nt], 0, 0, 0);
            }
        }

        // -- softmax numerators (no max: |e*log2e| <= 4.62) -> AT (bf16) --
#pragma unroll
        for (int rg = 0; rg < 4; ++rg) {
            float p0 = __builtin_amdgcn_exp2f(vacc[0][rg]);
            float p1 = __builtin_amdgcn_exp2f(vacc[1][rg]);
            float p2 = __builtin_amdgcn_exp2f(vacc[2][rg]);
            float p3 = __builtin_amdgcn_exp2f(vacc[3][rg]);
            u32x2 d;
            d[0] = pkbf(p0, p1);
            d[1] = pkbf(p2, p3);
            *(u32x2m*)(wbd + AT + rg * ROWB) = d;       // unnormalized p
        }

        // -- read back p A-frags; ssum/dsum on the MFMA pipe --
        {
            short8 pa0 = *(const short8m*)(wbr + AT);
            short8 pa1 = *(const short8m*)(wbr + AT + 64);
            f32x4 z = {0.f, 0.f, 0.f, 0.f};
            f32x4 sacc = __builtin_amdgcn_mfma_f32_16x16x32_bf16(pa0, ones8, z, 0, 0, 0);
            sacc = __builtin_amdgcn_mfma_f32_16x16x32_bf16(pa1, ones8, sacc, 0, 0, 0);
            f32x4 dacc = __builtin_amdgcn_mfma_f32_16x16x32_bf16(pa0, axc0, z, 0, 0, 0);
            dacc = __builtin_amdgcn_mfma_f32_16x16x32_bf16(pa1, axc1, dacc, 0, 0, 0);

            // rinv[rg] = 1/ssum[rowb+rg]  (every lane, layout matches vacc)
            rinv[0] = __builtin_amdgcn_rcpf(sacc[0]);
            rinv[1] = __builtin_amdgcn_rcpf(sacc[1]);
            rinv[2] = __builtin_amdgcn_rcpf(sacc[2]);
            rinv[3] = __builtin_amdgcn_rcpf(sacc[3]);

            // out_t = diag(dacc)*rinv on diag lanes
            float dv = dacc[0];
            dv = (k3 == 1) ? dacc[1] : dv;
            dv = (k3 == 2) ? dacc[2] : dv;
            dv = (k3 == 3) ? dacc[3] : dv;
            float rv = rinv[0];
            rv = (k3 == 1) ? rinv[1] : rv;
            rv = (k3 == 2) ? rinv[2] : rv;
            rv = (k3 == 3) ? rinv[3] : rv;
            if (isdiag) {
                if (OUTWS) op[t] = dv * rv;
                else       op[(size_t)t * Hsz] = dv * rv;
            }
        }
    }
}

// ws[H][B][T] -> out[B][T][H], 64x64 (t,h) tiles per b
__global__ __launch_bounds__(256, 4)
void out_transpose(const float* __restrict__ ws, float* __restrict__ outg) {
    __shared__ float tile[64][65];
    const int t0 = blockIdx.x * 64;
    const int h0 = blockIdx.y * 64;
    const int b  = blockIdx.z;
    const int tx = threadIdx.x & 63;
    const int wy = threadIdx.x >> 6;
#pragma unroll
    for (int i = 0; i < 16; ++i) {
        int hr = wy * 16 + i;
        tile[hr][tx] = ws[((size_t)(h0 + hr) * Bsz + b) * Tsz + t0 + tx];
    }
    __syncthreads();
#pragma unroll
    for (int i = 0; i < 16; ++i) {
        int tt = wy * 16 + i;
        outg[((size_t)b * Tsz + t0 + tt) * Hsz + h0 + tx] = tile[tx][tt];
    }
}

extern "C" void kernel_launch(void* const* d_in, const int* in_sizes, int n_in,
                              void* d_out, int out_size, void* d_ws, size_t ws_size,
                              hipStream_t stream) {
    // setup_inputs order: x, weight_att, weight_input, weight_e
    const float* x     = (const float*)d_in[0];
    const float* w_att = (const float*)d_in[1];
    const float* w_in  = (const float*)d_in[2];
    const float* w_e   = (const float*)d_in[3];
    float* out = (float*)d_out;

    const size_t XB = (size_t)Bsz * Tsz * Csz * sizeof(unsigned short);  // 33.5 MB
    const size_t OB = (size_t)Bsz * Tsz * Hsz * sizeof(float);           // 134 MB
    unsigned short* xb  = (unsigned short*)d_ws;
    float*          ows = (float*)((char*)d_ws + XB);

    const int xblocks = Bsz * Tsz * 8 / 256;      // 8192
    dim3 scan_grid(Hsz * (Bsz / 64));             // 1024 WGs of 4 waves

    if (ws_size >= XB + OB) {
        x_to_bf16_perm<<<xblocks, 256, 0, stream>>>(x, xb);
        attn_scan<true, true><<<scan_grid, 256, 0, stream>>>(x, xb, w_att, w_in, w_e, out, ows);
        dim3 tg(Tsz / 64, Hsz / 64, Bsz);
        out_transpose<<<tg, 256, 0, stream>>>(ows, out);
    } else if (ws_size >= XB) {
        x_to_bf16_perm<<<xblocks, 256, 0, stream>>>(x, xb);
        attn_scan<true, false><<<scan_grid, 256, 0, stream>>>(x, xb, w_att, w_in, w_e, out, nullptr);
    } else {
        attn_scan<false, false><<<scan_grid, 256, 0, stream>>>(x, nullptr, w_att, w_in, w_e, out, nullptr);
    }
}

// Round 8
// 1283.136 us; speedup vs baseline: 1.4563x; 1.0170x over previous
//
#include <hip/hip_runtime.h>

// ---------------------------------------------------------------------------
// Recurrent attention scan. B=512 T=512 C=64 H=128.
// 256-thread WG = 4 waves, SAME h, 4 different 16-row b-tiles. grid = 1024.
//
// Round 8 = round 6 (passed, 1305us) + PURE SCHEDULING HINTS ONLY (zero
// dataflow change -> numerically bit-identical to round 6):
//  (1) one-time s_sleep stagger keyed blockIdx%3 (~0/1470/2940 cy = thirds
//      of the ~4400cy per-wave step). Rationale: VALUBusy+MfmaUtil == 100%
//      for 3 passing rounds -> the 3 resident waves/SIMD are phase-locked
//      (identical barrier-free code, same start): all VALU together, then
//      all MFMA together; pipes sum instead of overlap. Desync lets wave
//      A's VALU run under wave B's MFMA. Success: VALUBusy+MfmaUtil>=110%.
//  (2) s_setprio(1) around each MFMA cluster (att/x/phaseB/sums): once
//      desynced, the MFMA-phase wave wins issue arbitration (T5 regime:
//      independent waves, no in-loop barriers).
// History note: round 7 (sums-merge) and rounds 4/5 (Win->LDS) fail
// numerically despite clean static verification -> dataflow rewrites on
// this kernel are high-risk; this round is deliberately risk-free.
// ---------------------------------------------------------------------------

constexpr int Bsz = 512, Tsz = 512, Csz = 64, Hsz = 128;

typedef __attribute__((ext_vector_type(8))) short short8;
typedef __attribute__((may_alias)) short8 short8m;
typedef __attribute__((ext_vector_type(4))) float f32x4;
typedef __attribute__((ext_vector_type(2))) unsigned int u32x2;
typedef __attribute__((may_alias)) u32x2 u32x2m;

#define LOG2E     1.44269504088896f
#define SCALE_CAT 2.88539008177793f   // 2*log2e

// per-wave LDS region byte offsets inside priv[wave][4608]
#define AT 0        // att tile (unnormalized p) [16][72] u16, slot-permuted
#define YT 2304     // tanh tile                 [16][72] u16
#define ROWB 144    // 72 u16 row pitch (bytes)

__device__ __forceinline__ unsigned short f2bf_rn(float f) {
    return (unsigned short)((__float_as_uint(f) + 0x8000u) >> 16);
}
__device__ __forceinline__ unsigned int pkbf(float lo, float hi) {
    unsigned int r;
    asm("v_cvt_pk_bf16_f32 %0, %1, %2" : "=v"(r) : "v"(lo), "v"(hi));
    return r;
}

// x[b][t][c] f32 -> xb[btile][t][row16][64] bf16, slot-permuted:
// slot s holds c = (s>>2) + (s&3)*16
__global__ __launch_bounds__(256, 4)
void x_to_bf16_perm(const float* __restrict__ x, unsigned short* __restrict__ xb) {
    int g = blockIdx.x * 256 + threadIdx.x;      // B*T*8 threads, 8 slots each
    int row = g >> 3, k = g & 7;                 // row = b*512 + t
    int b = row >> 9, t = row & 511;
    const float* src = x + (size_t)row * 64;
    short8 f;
#pragma unroll
    for (int a = 0; a < 4; ++a) {
        float2 w = *(const float2*)(src + a * 16 + 2 * k);  // c = a*16+2k, +1
        f[a]     = (short)f2bf_rn(w.x);   // slot 8k+a   -> c = a*16+2k
        f[4 + a] = (short)f2bf_rn(w.y);   // slot 8k+4+a -> c = a*16+2k+1
    }
    size_t ob = ((size_t)((b >> 4) * Tsz + t) * 16 + (b & 15)) * 64 + k * 8;
    *(short8m*)(xb + ob) = f;
}

// !XPRE fallback: gather one x A-frag pair straight from f32 x (slow path)
__device__ __forceinline__ void load_xfrag_f32(const float* src, int quad,
                                               short8& f0, short8& f1) {
#pragma unroll
    for (int hh = 0; hh < 2; ++hh) {
        short8 f;
        const int K = hh * 8 + quad * 2;
#pragma unroll
        for (int m = 0; m < 4; ++m) {
            float2 w = *(const float2*)(src + K + 16 * m);
            f[m]     = (short)f2bf_rn(w.x);
            f[m + 4] = (short)f2bf_rn(w.y);
        }
        if (hh == 0) f0 = f; else f1 = f;
    }
}

template<bool XPRE, bool OUTWS>
__global__ __launch_bounds__(256, 4)
void attn_scan(const float* __restrict__ xg,
               const unsigned short* __restrict__ xbg,
               const float* __restrict__ w_att,
               const float* __restrict__ w_in,
               const float* __restrict__ w_e,
               float* __restrict__ outg,
               float* __restrict__ outws)
{
    __shared__ __align__(16) unsigned short wefs[4096];   // We frags (shared, same h)
    __shared__ __align__(16) char priv[4][4608];          // wave-private AT+YT

    const int h     = blockIdx.x & (Hsz - 1);
    const int btg   = blockIdx.x >> 7;
    const int wave  = threadIdx.x >> 6;
    const int lane  = threadIdx.x & 63;
    const int btile = btg * 4 + wave;
    const int b0    = btile * 16;

    const int l15  = lane & 15;
    const int quad = lane >> 4;
    const int rowb = quad * 4;

    // ---- cooperative We -> LDS, fragment layout, slot-permuted k, *log2e
    {
        const float* weh = w_e + (size_t)h * Csz * Csz;
#pragma unroll
        for (int i = 0; i < 2; ++i) {
            int tp = threadIdx.x * 2 + i;              // 0..511 tuples
            int ntks = tp >> 6, q = (tp >> 4) & 3, l = tp & 15;
            int ks = ntks & 1, nt = ntks >> 1;
            int m = ks * 4 + q;
            const float* srcw = weh + (nt * 16 + l) * 64;
            short8 f;
#pragma unroll
            for (int j = 0; j < 8; ++j) {
                int kk = ((j & 3) << 4) + 2 * m + (j >> 2);   // = c(slot)
                f[j] = (short)f2bf_rn(srcw[kk] * LOG2E);
            }
            *(short8m*)(wefs + tp * 8) = f;
        }
    }

    // ---- Wcat (Win | Watt) -> registers, slot-permuted k, *2log2e
    short8 wcat[4][4];
    {
        const float* winh = w_in  + (size_t)h * Csz * Csz;
        const float* wath = w_att + (size_t)h * Csz * Csz;
#pragma unroll
        for (int nt = 0; nt < 4; ++nt) {
            const int c = nt * 16 + l15;
#pragma unroll
            for (int ks = 0; ks < 4; ++ks) {
                const float* srcw = ((ks < 2) ? winh : wath) + c * 64;
                const int m = (ks & 1) * 4 + quad;
                short8 f;
#pragma unroll
                for (int j = 0; j < 8; ++j) {
                    int kk = ((j & 3) << 4) + 2 * m + (j >> 2);
                    f[j] = (short)f2bf_rn(srcw[kk] * SCALE_CAT);
                }
                wcat[nt][ks] = f;
            }
        }
    }

    __syncthreads();   // wefs ready; only barrier in the kernel

    // ---- phase-desync stagger: break 3-wave/SIMD lockstep (pure hint,
    //      zero dataflow impact). Thirds of the ~4400cy per-wave step.
    {
        int ph = blockIdx.x % 3;
        if (ph == 1)      __builtin_amdgcn_s_sleep(23);   // ~1470 cy
        else if (ph == 2) __builtin_amdgcn_s_sleep(46);   // ~2940 cy
    }

    char* wb  = priv[wave];
    char* wbr = wb + l15 * ROWB + quad * 16;        // A-frag b128 read base
    char* wbd = wb + quad * (4 * ROWB) + l15 * 8;   // per-row b64 write base
    const unsigned short* wfpe = wefs + quad * 128 + l15 * 8;  // We B-frag base

    // ones B-frag (bf16 1.0): for ssum MFMA
    short8 ones8;
#pragma unroll
    for (int j = 0; j < 8; ++j) ones8[j] = (short)0x3F80;

    // ---- init att0 = 1/64 (bf16 0x3C80): normalized, so rinv starts at 1
    {
        short8 kinit;
#pragma unroll
        for (int j = 0; j < 8; ++j) kinit[j] = (short)0x3C80;
#pragma unroll
        for (int i = 0; i < 3; ++i) {
            int idx = i * 64 + lane;
            if (idx < 144) *(short8m*)(wb + AT + idx * 16) = kinit;
        }
    }

    // ---- x A-frag source (frag-addressable permuted layout)
    const unsigned short* xfp = nullptr;
    if (XPRE)
        xfp = xbg + (size_t)btile * Tsz * 1024 + l15 * 64 + quad * 8;

    // ---- out addressing: diag lanes (l15>>2==quad) own row rowb+(l15&3)
    const int  k3     = l15 & 3;
    const int  orow   = rowb + k3;
    const bool isdiag = ((l15 >> 2) == quad);
    float* op;
    if (OUTWS) op = outws + ((size_t)h * Bsz + b0 + orow) * Tsz;
    else       op = outg + (size_t)(b0 + orow) * (Tsz * Hsz) + h;

    float rinv[4] = {1.f, 1.f, 1.f, 1.f};   // 1/ssum of prev step's p

    for (int t = 0; t < Tsz; ++t) {
        // -- load x_t frags --
        short8 axc0, axc1;
        if (XPRE) {
            axc0 = *(const short8m*)(xfp + (size_t)t * 1024);
            axc1 = *(const short8m*)(xfp + (size_t)t * 1024 + 32);
        } else {
            load_xfrag_f32(xg + ((size_t)(b0 + l15) * Tsz + t) * 64, quad, axc0, axc1);
        }

        f32x4 vacc[4];
        // -- phase A: vacc = (p . Watt^T)*rinv + x . Win^T (pre-scaled 2log2e)
        {
            short8 aa0 = *(const short8m*)(wbr + AT);
            short8 aa1 = *(const short8m*)(wbr + AT + 64);
            f32x4 z = {0.f, 0.f, 0.f, 0.f};
            __builtin_amdgcn_s_setprio(1);
#pragma unroll
            for (int nt = 0; nt < 4; ++nt) {
                vacc[nt] = __builtin_amdgcn_mfma_f32_16x16x32_bf16(aa0, wcat[nt][2], z, 0, 0, 0);
                vacc[nt] = __builtin_amdgcn_mfma_f32_16x16x32_bf16(aa1, wcat[nt][3], vacc[nt], 0, 0, 0);
            }
            __builtin_amdgcn_s_setprio(0);
#pragma unroll
            for (int nt = 0; nt < 4; ++nt)
#pragma unroll
                for (int rg = 0; rg < 4; ++rg)
                    vacc[nt][rg] *= rinv[rg];
            __builtin_amdgcn_s_setprio(1);
#pragma unroll
            for (int nt = 0; nt < 4; ++nt) {
                vacc[nt] = __builtin_amdgcn_mfma_f32_16x16x32_bf16(axc0, wcat[nt][0], vacc[nt], 0, 0, 0);
                vacc[nt] = __builtin_amdgcn_mfma_f32_16x16x32_bf16(axc1, wcat[nt][1], vacc[nt], 0, 0, 0);
            }
            __builtin_amdgcn_s_setprio(0);
        }

        // -- tanh: y = 1 - 2/(exp2(acc)+1); packed pairs -> Ytile (b64/row) --
#pragma unroll
        for (int rg = 0; rg < 4; ++rg) {
            float E0 = __builtin_amdgcn_exp2f(vacc[0][rg]);
            float E1 = __builtin_amdgcn_exp2f(vacc[1][rg]);
            float E2 = __builtin_amdgcn_exp2f(vacc[2][rg]);
            float E3 = __builtin_amdgcn_exp2f(vacc[3][rg]);
            float y0 = fmaf(-2.f, __builtin_amdgcn_rcpf(E0 + 1.f), 1.f);
            float y1 = fmaf(-2.f, __builtin_amdgcn_rcpf(E1 + 1.f), 1.f);
            float y2 = fmaf(-2.f, __builtin_amdgcn_rcpf(E2 + 1.f), 1.f);
            float y3 = fmaf(-2.f, __builtin_amdgcn_rcpf(E3 + 1.f), 1.f);
            u32x2 d;
            d[0] = pkbf(y0, y1);
            d[1] = pkbf(y2, y3);
            *(u32x2m*)(wbd + YT + rg * ROWB) = d;
        }

        // -- phase B: e = y . We^T (K=64), We frags from shared LDS --
        {
            short8 y0 = *(const short8m*)(wbr + YT);
            short8 y1 = *(const short8m*)(wbr + YT + 64);
            f32x4 z = {0.f, 0.f, 0.f, 0.f};
            __builtin_amdgcn_s_setprio(1);
#pragma unroll
            for (int nt = 0; nt < 4; ++nt) {
                short8 w0 = *(const short8m*)(wfpe + (nt * 2) * 512);
                short8 w1 = *(const short8m*)(wfpe + (nt * 2 + 1) * 512);
                vacc[nt] = __builtin_amdgcn_mfma_f32_16x16x32_bf16(y0, w0, z, 0, 0, 0);
                vacc[nt] = __builtin_amdgcn_mfma_f32_16x16x32_bf16(y1, w1, vacc[nt], 0, 0, 0);
            }
            __builtin_amdgcn_s_setprio(0);
        }

        // -- softmax numerators (no max: |e*log2e| <= 4.62) -> AT (bf16) --
#pragma unroll
        for (int rg = 0; rg < 4; ++rg) {
            float p0 = __builtin_amdgcn_exp2f(vacc[0][rg]);
            float p1 = __builtin_amdgcn_exp2f(vacc[1][rg]);
            float p2 = __builtin_amdgcn_exp2f(vacc[2][rg]);
            float p3 = __builtin_amdgcn_exp2f(vacc[3][rg]);
            u32x2 d;
            d[0] = pkbf(p0, p1);
            d[1] = pkbf(p2, p3);
            *(u32x2m*)(wbd + AT + rg * ROWB) = d;       // unnormalized p
        }

        // -- read back p A-frags; ssum/dsum on the MFMA pipe --
        {
            short8 pa0 = *(const short8m*)(wbr + AT);
            short8 pa1 = *(const short8m*)(wbr + AT + 64);
            f32x4 z = {0.f, 0.f, 0.f, 0.f};
            __builtin_amdgcn_s_setprio(1);
            f32x4 sacc = __builtin_amdgcn_mfma_f32_16x16x32_bf16(pa0, ones8, z, 0, 0, 0);
            sacc = __builtin_amdgcn_mfma_f32_16x16x32_bf16(pa1, ones8, sacc, 0, 0, 0);
            f32x4 dacc = __builtin_amdgcn_mfma_f32_16x16x32_bf16(pa0, axc0, z, 0, 0, 0);
            dacc = __builtin_amdgcn_mfma_f32_16x16x32_bf16(pa1, axc1, dacc, 0, 0, 0);
            __builtin_amdgcn_s_setprio(0);

            // rinv[rg] = 1/ssum[rowb+rg]  (every lane, layout matches vacc)
            rinv[0] = __builtin_amdgcn_rcpf(sacc[0]);
            rinv[1] = __builtin_amdgcn_rcpf(sacc[1]);
            rinv[2] = __builtin_amdgcn_rcpf(sacc[2]);
            rinv[3] = __builtin_amdgcn_rcpf(sacc[3]);

            // out_t = diag(dacc)*rinv on diag lanes
            float dv = dacc[0];
            dv = (k3 == 1) ? dacc[1] : dv;
            dv = (k3 == 2) ? dacc[2] : dv;
            dv = (k3 == 3) ? dacc[3] : dv;
            float rv = rinv[0];
            rv = (k3 == 1) ? rinv[1] : rv;
            rv = (k3 == 2) ? rinv[2] : rv;
            rv = (k3 == 3) ? rinv[3] : rv;
            if (isdiag) {
                if (OUTWS) op[t] = dv * rv;
                else       op[(size_t)t * Hsz] = dv * rv;
            }
        }
    }
}

// ws[H][B][T] -> out[B][T][H], 64x64 (t,h) tiles per b
__global__ __launch_bounds__(256, 4)
void out_transpose(const float* __restrict__ ws, float* __restrict__ outg) {
    __shared__ float tile[64][65];
    const int t0 = blockIdx.x * 64;
    const int h0 = blockIdx.y * 64;
    const int b  = blockIdx.z;
    const int tx = threadIdx.x & 63;
    const int wy = threadIdx.x >> 6;
#pragma unroll
    for (int i = 0; i < 16; ++i) {
        int hr = wy * 16 + i;
        tile[hr][tx] = ws[((size_t)(h0 + hr) * Bsz + b) * Tsz + t0 + tx];
    }
    __syncthreads();
#pragma unroll
    for (int i = 0; i < 16; ++i) {
        int tt = wy * 16 + i;
        outg[((size_t)b * Tsz + t0 + tt) * Hsz + h0 + tx] = tile[tx][tt];
    }
}

extern "C" void kernel_launch(void* const* d_in, const int* in_sizes, int n_in,
                              void* d_out, int out_size, void* d_ws, size_t ws_size,
                              hipStream_t stream) {
    // setup_inputs order: x, weight_att, weight_input, weight_e
    const float* x     = (const float*)d_in[0];
    const float* w_att = (const float*)d_in[1];
    const float* w_in  = (const float*)d_in[2];
    const float* w_e   = (const float*)d_in[3];
    float* out = (float*)d_out;

    const size_t XB = (size_t)Bsz * Tsz * Csz * sizeof(unsigned short);  // 33.5 MB
    const size_t OB = (size_t)Bsz * Tsz * Hsz * sizeof(float);           // 134 MB
    unsigned short* xb  = (unsigned short*)d_ws;
    float*          ows = (float*)((char*)d_ws + XB);

    const int xblocks = Bsz * Tsz * 8 / 256;      // 8192
    dim3 scan_grid(Hsz * (Bsz / 64));             // 1024 WGs of 4 waves

    if (ws_size >= XB + OB) {
        x_to_bf16_perm<<<xblocks, 256, 0, stream>>>(x, xb);
        attn_scan<true, true><<<scan_grid, 256, 0, stream>>>(x, xb, w_att, w_in, w_e, out, ows);
        dim3 tg(Tsz / 64, Hsz / 64, Bsz);
        out_transpose<<<tg, 256, 0, stream>>>(ows, out);
    } else if (ws_size >= XB) {
        x_to_bf16_perm<<<xblocks, 256, 0, stream>>>(x, xb);
        attn_scan<true, false><<<scan_grid, 256, 0, stream>>>(x, xb, w_att, w_in, w_e, out, nullptr);
    } else {
        attn_scan<false, false><<<scan_grid, 256, 0, stream>>>(x, nullptr, w_att, w_in, w_e, out, nullptr);
    }
}